// Round 1
// baseline (255.771 us; speedup 1.0000x reference)
//
#include <hip/hip_runtime.h>
#include <math.h>

typedef unsigned short u16;
typedef __attribute__((ext_vector_type(8))) __bf16 bf16x8;
typedef __attribute__((ext_vector_type(8))) u16 u16x8;
typedef __attribute__((ext_vector_type(4))) u16 u16x4;
typedef __attribute__((ext_vector_type(4))) float f32x4;

#define GLOAD16(gp, lp)                                                        \
  __builtin_amdgcn_global_load_lds(                                            \
      (const __attribute__((address_space(1))) unsigned int*)(gp),             \
      (__attribute__((address_space(3))) unsigned int*)(lp), 16, 0, 0)

__device__ __forceinline__ u16 bf16r(float f) {
  unsigned u = __float_as_uint(f);
  u += 0x7fff + ((u >> 16) & 1);
  return (u16)(u >> 16);
}

__device__ __forceinline__ bf16x8 ldfrag(const u16* p) {
  return __builtin_bit_cast(bf16x8, *(const u16x8*)p);
}

__device__ __forceinline__ f32x4 mfma16(bf16x8 a, bf16x8 b, f32x4 c) {
  return __builtin_amdgcn_mfma_f32_16x16x32_bf16(a, b, c, 0, 0, 0);
}

// ---------------- constants ----------------
// B=2 S=2048 D_MODEL=1024 H=16 DKV=64, inner=1024
#define QKV_MAT_STRIDE (2 * 16 * 2048 * 64)  // elements per one of q/k/v

// ---------------- LUT: T5 relative bucket of rel in [-4096,4096] -----------
__global__ void k_build_lut(signed char* __restrict__ lut8) {
  int i = blockIdx.x * 256 + threadIdx.x;
  if (i > 8192) return;
  int rel = i - 4096;
  int ret = rel > 0 ? 16 : 0;
  int n = rel < 0 ? -rel : rel;
  int bucket;
  if (n < 8) {
    bucket = n;
  } else {
    // double precision: boundary n (16,32,...,1024) land exactly on integers
    int vl = 8 + (int)(log((double)n / 8.0) / log(16.0) * 8.0);
    bucket = vl > 15 ? 15 : vl;
  }
  lut8[i] = (signed char)(ret + bucket);
}

// ---------------- per-key bias -------------------
__global__ void k_kbias(const float* __restrict__ mask, const float* __restrict__ ss,
                        const int* __restrict__ nd, float* __restrict__ kb) {
  int i = blockIdx.x * 256 + threadIdx.x;  // < 4096
  kb[i] = -1000.0f * (1.0f - mask[i]) + logf(ss[i] + 1e-4f) + logf((float)nd[i] + 1e-4f);
}

// ---------------- weight transpose fp32 [k][n] -> bf16 [n][k] --------------
__global__ __launch_bounds__(256) void k_transpose(
    const float* __restrict__ Wq, const float* __restrict__ Wk,
    const float* __restrict__ Wv, const float* __restrict__ Wo,
    u16* __restrict__ wtqkv, u16* __restrict__ wto) {
  int z = blockIdx.z;
  const float* W = (z == 0) ? Wq : (z == 1) ? Wk : (z == 2) ? Wv : Wo;
  u16* Wt = (z < 3) ? (wtqkv + (size_t)z * 1024 * 1024) : wto;
  __shared__ float tile[32][33];
  int n0 = blockIdx.x * 32, k0 = blockIdx.y * 32;
  int tx = threadIdx.x, ty = threadIdx.y;  // (32,8)
#pragma unroll
  for (int j = 0; j < 4; ++j)
    tile[ty + 8 * j][tx] = W[(size_t)(k0 + ty + 8 * j) * 1024 + n0 + tx];
  __syncthreads();
#pragma unroll
  for (int j = 0; j < 4; ++j)
    Wt[(size_t)(n0 + ty + 8 * j) * 1024 + k0 + tx] = bf16r(tile[tx][ty + 8 * j]);
}

// ---------------- RMSNorm (T5 LayerNorm) -> bf16 --------------------------
__global__ __launch_bounds__(256) void k_rmsnorm(const float* __restrict__ x,
                                                 const float* __restrict__ w,
                                                 u16* __restrict__ out) {
  int row = blockIdx.x;  // 0..4095
  int t = threadIdx.x;
  const float4 v = ((const float4*)(x + (size_t)row * 1024))[t];
  float ss = v.x * v.x + v.y * v.y + v.z * v.z + v.w * v.w;
#pragma unroll
  for (int o = 1; o < 64; o <<= 1) ss += __shfl_xor(ss, o);
  __shared__ float wsum[4];
  if ((t & 63) == 0) wsum[t >> 6] = ss;
  __syncthreads();
  float tot = wsum[0] + wsum[1] + wsum[2] + wsum[3];
  float rs = rsqrtf(tot * (1.0f / 1024.0f) + 1e-6f);
  const float4 wv = ((const float4*)w)[t];
  u16x4 o4;
  o4[0] = bf16r(v.x * rs * wv.x);
  o4[1] = bf16r(v.y * rs * wv.y);
  o4[2] = bf16r(v.z * rs * wv.z);
  o4[3] = bf16r(v.w * rs * wv.w);
  *(u16x4*)(out + (size_t)row * 1024 + t * 4) = o4;
}

// ---------------- 128x128 bf16 MFMA GEMM, K=1024, M=4096, N=1024 ----------
// A [4096][1024] bf16 row-major; Bt [N][K] bf16 (z-strided for QKV).
// mode 0: out -> qkv bf16 in [3][B*H][S][64] head layout
// mode 1: out -> fp32 row-major d_out
__global__ __launch_bounds__(256) void k_gemm(const u16* __restrict__ A,
                                              const u16* __restrict__ Bt,
                                              u16* __restrict__ outB,
                                              float* __restrict__ outF, int mode) {
  const int t = threadIdx.x, lane = t & 63, w = t >> 6;
  const int wr = w >> 1, wc = w & 1;
  const int m0 = blockIdx.y << 7, n0 = blockIdx.x << 7;
  const int z = blockIdx.z;
  const u16* Btm = Bt + (size_t)z * (1024 * 1024);
  __shared__ u16 As[8192], Bs[8192];

  f32x4 acc[4][4];
#pragma unroll
  for (int i = 0; i < 4; ++i)
#pragma unroll
    for (int j = 0; j < 4; ++j) acc[i][j] = (f32x4){0.f, 0.f, 0.f, 0.f};

  for (int k0 = 0; k0 < 1024; k0 += 64) {
#pragma unroll
    for (int i = 0; i < 4; ++i) {
      const int o = ((i * 4 + w) * 64 + lane) << 4;  // LDS byte offset (linear)
      const int r = o >> 7;
      const int cb = (o & 127) ^ ((r & 7) << 4);  // pre-swizzled global source
      GLOAD16((const char*)A + (size_t)(m0 + r) * 2048 + (k0 << 1) + cb,
              (char*)As + (i * 4 + w) * 1024);
      GLOAD16((const char*)Btm + (size_t)(n0 + r) * 2048 + (k0 << 1) + cb,
              (char*)Bs + (i * 4 + w) * 1024);
    }
    __syncthreads();
#pragma unroll
    for (int kk = 0; kk < 2; ++kk) {
      bf16x8 af[4], bfr[4];
#pragma unroll
      for (int mi = 0; mi < 4; ++mi) {
        int r = (wr << 6) + (mi << 4) + (lane & 15);
        int cb = ((kk << 6) + ((lane >> 4) << 4)) ^ ((r & 7) << 4);
        af[mi] = ldfrag(As + (((r << 7) + cb) >> 1));
      }
#pragma unroll
      for (int ni = 0; ni < 4; ++ni) {
        int r = (wc << 6) + (ni << 4) + (lane & 15);
        int cb = ((kk << 6) + ((lane >> 4) << 4)) ^ ((r & 7) << 4);
        bfr[ni] = ldfrag(Bs + (((r << 7) + cb) >> 1));
      }
#pragma unroll
      for (int mi = 0; mi < 4; ++mi)
#pragma unroll
        for (int ni = 0; ni < 4; ++ni)
          acc[mi][ni] = mfma16(af[mi], bfr[ni], acc[mi][ni]);
    }
    __syncthreads();
  }

  const int rbase = (lane >> 4) << 2;
  const int cl = lane & 15;
  if (mode == 0) {
    u16* dst = outB + (size_t)z * QKV_MAT_STRIDE;
#pragma unroll
    for (int mi = 0; mi < 4; ++mi)
#pragma unroll
      for (int ni = 0; ni < 4; ++ni)
#pragma unroll
        for (int i = 0; i < 4; ++i) {
          int rg = m0 + (wr << 6) + (mi << 4) + rbase + i;  // b*2048+s
          int cg = n0 + (wc << 6) + (ni << 4) + cl;         // h*64+d
          int b = rg >> 11, s = rg & 2047, h = cg >> 6, d = cg & 63;
          dst[(((size_t)(b * 16 + h)) * 2048 + s) * 64 + d] = bf16r(acc[mi][ni][i]);
        }
  } else {
#pragma unroll
    for (int mi = 0; mi < 4; ++mi)
#pragma unroll
      for (int ni = 0; ni < 4; ++ni)
#pragma unroll
        for (int i = 0; i < 4; ++i) {
          int rg = m0 + (wr << 6) + (mi << 4) + rbase + i;
          int cg = n0 + (wc << 6) + (ni << 4) + cl;
          outF[(size_t)rg * 1024 + cg] = acc[mi][ni][i];
        }
  }
}

// ---------------- flash attention: 64 q-rows / block, K/V chunks of 64 ----
__global__ __launch_bounds__(256) void k_attn(
    const u16* __restrict__ qkv, const int* __restrict__ positions,
    const float* __restrict__ kbias, const signed char* __restrict__ lut8,
    const float* __restrict__ rel_emb, u16* __restrict__ ctx) {
  const int t = threadIdx.x, lane = t & 63, w = t >> 6;
  const int qb = blockIdx.x, bh = blockIdx.y;
  const int b = bh >> 4, h = bh & 15;
  const size_t hb = (size_t)bh * (2048 * 64);
  const u16* Qg = qkv + hb + (size_t)qb * 64 * 64;
  const u16* Kg = qkv + (size_t)QKV_MAT_STRIDE + hb;
  const u16* Vg = qkv + (size_t)2 * QKV_MAT_STRIDE + hb;

  __shared__ u16 Qs[4096], Ks[4096], Vts[4096];
  __shared__ u16 Ps[4][1024];
  __shared__ float relb[32];
  __shared__ float kbs[64];
  __shared__ int poss[64];
  __shared__ signed char l8[8224];

  for (int i = t; i < 8193; i += 256) l8[i] = lut8[i];
  if (t < 32) relb[t] = rel_emb[t * 16 + h];
#pragma unroll
  for (int i = 0; i < 2; ++i) {  // stage Q (8KB), pre-swizzled source
    const int o = ((i * 4 + w) * 64 + lane) << 4;
    const int r = o >> 7;
    const int cb = (o & 127) ^ ((r & 7) << 4);
    GLOAD16((const char*)Qg + (r << 7) + cb, (char*)Qs + (i * 4 + w) * 1024);
  }
  __syncthreads();

  bf16x8 qa[2];  // hoisted Q A-fragments (constant over k-chunks)
  {
    const int r = (w << 4) + (lane & 15);
#pragma unroll
    for (int kk = 0; kk < 2; ++kk) {
      int cb = ((kk << 6) + ((lane >> 4) << 4)) ^ ((r & 7) << 4);
      qa[kk] = ldfrag(Qs + (((r << 7) + cb) >> 1));
    }
  }
  const int qrow0 = qb * 64 + (w << 4) + ((lane >> 4) << 2);
  int pq[4];
#pragma unroll
  for (int i = 0; i < 4; ++i) pq[i] = positions[b * 2048 + qrow0 + i];

  float m_run[4] = {-INFINITY, -INFINITY, -INFINITY, -INFINITY};
  float l_run[4] = {0.f, 0.f, 0.f, 0.f};
  f32x4 oacc[4];
#pragma unroll
  for (int i = 0; i < 4; ++i) oacc[i] = (f32x4){0.f, 0.f, 0.f, 0.f};

  for (int kc = 0; kc < 2048; kc += 64) {
#pragma unroll
    for (int i = 0; i < 2; ++i) {  // stage K chunk
      const int o = ((i * 4 + w) * 64 + lane) << 4;
      const int r = o >> 7;
      const int cb = (o & 127) ^ ((r & 7) << 4);
      GLOAD16((const char*)Kg + (size_t)(kc + r) * 128 + cb,
              (char*)Ks + (i * 4 + w) * 1024);
    }
    {  // stage V transposed: Vts[d][kc], swizzled
      const int r = t & 63, d0 = (t >> 6) << 4;
      const u16* src = Vg + (size_t)(kc + r) * 64 + d0;
      u16x8 v0 = *(const u16x8*)src;
      u16x8 v1 = *(const u16x8*)(src + 8);
#pragma unroll
      for (int e = 0; e < 8; ++e) {
        int d = d0 + e;
        int cb = (r << 1) ^ ((d & 7) << 4);
        Vts[(d << 6) + (cb >> 1)] = v0[e];
      }
#pragma unroll
      for (int e = 0; e < 8; ++e) {
        int d = d0 + 8 + e;
        int cb = (r << 1) ^ ((d & 7) << 4);
        Vts[(d << 6) + (cb >> 1)] = v1[e];
      }
    }
    if (t < 64) {
      poss[t] = positions[b * 2048 + kc + t];
      kbs[t] = kbias[b * 2048 + kc + t];
    }
    __syncthreads();

    // S = Q K^T  (per wave: 16 q-rows x 64 k-cols)
    f32x4 sc[4];
#pragma unroll
    for (int sub = 0; sub < 4; ++sub) {
      f32x4 a = (f32x4){0.f, 0.f, 0.f, 0.f};
#pragma unroll
      for (int kk = 0; kk < 2; ++kk) {
        int r = (sub << 4) + (lane & 15);
        int cb = ((kk << 6) + ((lane >> 4) << 4)) ^ ((r & 7) << 4);
        a = mfma16(qa[kk], ldfrag(Ks + (((r << 7) + cb) >> 1)), a);
      }
      sc[sub] = a;
    }
    // + rel-pos bias + key bias
#pragma unroll
    for (int sub = 0; sub < 4; ++sub) {
      int ki = (sub << 4) + (lane & 15);
      float kb = kbs[ki];
      int pk = poss[ki];
#pragma unroll
      for (int i = 0; i < 4; ++i)
        sc[sub][i] += relb[(int)l8[pk - pq[i] + 4096]] + kb;
    }
    // online softmax (row = (lane>>4)*4+i, 16 lanes hold the 16 cols/subtile)
    float pm[4], scale[4], ps[4];
#pragma unroll
    for (int i = 0; i < 4; ++i) {
      pm[i] = fmaxf(fmaxf(sc[0][i], sc[1][i]), fmaxf(sc[2][i], sc[3][i]));
#pragma unroll
      for (int ofs = 1; ofs < 16; ofs <<= 1) pm[i] = fmaxf(pm[i], __shfl_xor(pm[i], ofs));
      float mn = fmaxf(m_run[i], pm[i]);
      scale[i] = __expf(m_run[i] - mn);
      m_run[i] = mn;
      ps[i] = 0.f;
    }
#pragma unroll
    for (int sub = 0; sub < 4; ++sub)
#pragma unroll
      for (int i = 0; i < 4; ++i) {
        float p = __expf(sc[sub][i] - m_run[i]);
        sc[sub][i] = p;
        ps[i] += p;
      }
#pragma unroll
    for (int i = 0; i < 4; ++i) {
#pragma unroll
      for (int ofs = 1; ofs < 16; ofs <<= 1) ps[i] += __shfl_xor(ps[i], ofs);
      l_run[i] = l_run[i] * scale[i] + ps[i];
    }
#pragma unroll
    for (int d2 = 0; d2 < 4; ++d2)
#pragma unroll
      for (int i = 0; i < 4; ++i) oacc[d2][i] *= scale[i];
    // P -> per-wave LDS (bf16, swizzled) for PV A-fragments
#pragma unroll
    for (int sub = 0; sub < 4; ++sub)
#pragma unroll
      for (int i = 0; i < 4; ++i) {
        int r = ((lane >> 4) << 2) + i;
        int cb = (((sub << 4) + (lane & 15)) << 1) ^ ((r & 7) << 4);
        Ps[w][(r << 6) + (cb >> 1)] = bf16r(sc[sub][i]);
      }
    // O += P V
#pragma unroll
    for (int kk = 0; kk < 2; ++kk) {
      int pr = lane & 15;
      int pcb = ((kk << 6) + ((lane >> 4) << 4)) ^ ((pr & 7) << 4);
      bf16x8 pa = ldfrag(&Ps[w][0] + (((pr << 7) + pcb) >> 1));
#pragma unroll
      for (int d2 = 0; d2 < 4; ++d2) {
        int vr = (d2 << 4) + (lane & 15);
        int vcb = ((kk << 6) + ((lane >> 4) << 4)) ^ ((vr & 7) << 4);
        oacc[d2] = mfma16(pa, ldfrag(Vts + (((vr << 7) + vcb) >> 1)), oacc[d2]);
      }
    }
    __syncthreads();
  }

  float inv[4];
#pragma unroll
  for (int i = 0; i < 4; ++i) inv[i] = 1.0f / l_run[i];
#pragma unroll
  for (int d2 = 0; d2 < 4; ++d2)
#pragma unroll
    for (int i = 0; i < 4; ++i) {
      int row = qrow0 + i;
      int d = (d2 << 4) + (lane & 15);
      ctx[((size_t)b * 2048 + row) * 1024 + h * 64 + d] = bf16r(oacc[d2][i] * inv[i]);
    }
}

// ---------------- launch ----------------
extern "C" void kernel_launch(void* const* d_in, const int* in_sizes, int n_in,
                              void* d_out, int out_size, void* d_ws, size_t ws_size,
                              hipStream_t stream) {
  const float* hs = (const float*)d_in[0];
  const int* pos = (const int*)d_in[1];
  const float* mask = (const float*)d_in[2];
  const float* ss = (const float*)d_in[3];
  const int* nd = (const int*)d_in[4];
  const float* lnw = (const float*)d_in[5];
  const float* Wq = (const float*)d_in[6];
  const float* Wk = (const float*)d_in[7];
  const float* Wv = (const float*)d_in[8];
  const float* Wo = (const float*)d_in[9];
  const float* rel = (const float*)d_in[10];

  char* ws = (char*)d_ws;
  // offsets (256-aligned)
  signed char* lut8 = (signed char*)ws;            //      0 .. 8448
  float* kb = (float*)(ws + 8448);                 //   8448 .. 24832
  u16* normed = (u16*)(ws + 24832);                //  +8 MB
  u16* wtqkv = (u16*)(ws + 8413440);               //  +6 MB
  u16* wto = (u16*)(ws + 14704896);                //  +2 MB
  u16* qkv = (u16*)(ws + 16802048);                //  +24 MB
  u16* ctx = (u16*)(ws + 41967872);                //  +8 MB  (end 50356480)
  if (ws_size < 50356480) return;  // loud failure instead of corruption

  k_build_lut<<<33, 256, 0, stream>>>(lut8);
  k_kbias<<<16, 256, 0, stream>>>(mask, ss, nd, kb);
  k_transpose<<<dim3(32, 32, 4), dim3(32, 8), 0, stream>>>(Wq, Wk, Wv, Wo, wtqkv, wto);
  k_rmsnorm<<<4096, 256, 0, stream>>>(hs, lnw, normed);
  k_gemm<<<dim3(8, 32, 3), 256, 0, stream>>>(normed, wtqkv, qkv, nullptr, 0);
  k_attn<<<dim3(32, 32), 256, 0, stream>>>(qkv, pos, kb, lut8, rel, ctx);
  k_gemm<<<dim3(8, 32, 1), 256, 0, stream>>>(ctx, wto, nullptr, (float*)d_out, 1);
}